// Round 2
// baseline (1101.048 us; speedup 1.0000x reference)
//
#include <hip/hip_runtime.h>
#include <hip/hip_bf16.h>
#include <stdint.h>

#define Bn 32
#define Ln 2048
#define Dn 64

typedef __bf16 bf16x8_t __attribute__((ext_vector_type(8)));
typedef float f32x4_t __attribute__((ext_vector_type(4)));

// ushort index into a [rows][64]-bf16 tile (128 B rows), XOR-swizzled (T2 / G4)
__device__ __forceinline__ int swzi(int row, int col) {
  return (((row << 7) + (col << 1)) ^ ((row & 7) << 4)) >> 1;
}

// Load 64 rows x 64 f32 from src, L2-normalize each row, store bf16 swizzled.
// 256 threads: 8 threads per row, each owns 8 contiguous floats -> one b128 LDS write.
__device__ __forceinline__ void stage_norm_tile(const float* __restrict__ src,
                                                __bf16* dst, int tid) {
#pragma unroll
  for (int half = 0; half < 2; ++half) {
    const int chunk = half * 256 + tid;
    const int row = chunk >> 3, h = chunk & 7;
    const float4* p = (const float4*)(src + row * 64 + h * 8);
    float4 x0 = p[0], x1 = p[1];
    float ss = x0.x * x0.x + x0.y * x0.y + x0.z * x0.z + x0.w * x0.w +
               x1.x * x1.x + x1.y * x1.y + x1.z * x1.z + x1.w * x1.w;
    ss += __shfl_xor(ss, 1);
    ss += __shfl_xor(ss, 2);
    ss += __shfl_xor(ss, 4);
    const float inv = 1.0f / fmaxf(sqrtf(ss), 1e-12f);
    bf16x8_t hv;
    hv[0] = (__bf16)(x0.x * inv); hv[1] = (__bf16)(x0.y * inv);
    hv[2] = (__bf16)(x0.z * inv); hv[3] = (__bf16)(x0.w * inv);
    hv[4] = (__bf16)(x1.x * inv); hv[5] = (__bf16)(x1.y * inv);
    hv[6] = (__bf16)(x1.z * inv); hv[7] = (__bf16)(x1.w * inv);
    *(bf16x8_t*)&dst[swzi(row, h * 8)] = hv;
  }
}

// Load 64(keys) x 64(feat) f32, store transposed bf16 [feat][key], swizzled.
__device__ __forceinline__ void stage_v_T(const float* __restrict__ src,
                                          __bf16* dst, int tid) {
  const int krow = tid >> 2, seg = tid & 3;
  const float4* p = (const float4*)(src + krow * 64) + seg * 4;
#pragma unroll
  for (int j = 0; j < 4; ++j) {
    float4 x = p[j];
    const int f = seg * 16 + j * 4;
    dst[swzi(f + 0, krow)] = (__bf16)x.x;
    dst[swzi(f + 1, krow)] = (__bf16)x.y;
    dst[swzi(f + 2, krow)] = (__bf16)x.z;
    dst[swzi(f + 3, krow)] = (__bf16)x.w;
  }
}

__global__ __launch_bounds__(256, 4)
void cosattn_kernel(const float* __restrict__ q, const float* __restrict__ kk,
                    const float* __restrict__ v, const int* __restrict__ mask,
                    float* __restrict__ out, float* __restrict__ attn) {
  __shared__ __align__(16) __bf16 QS[4096];    // Qn [64][64] swz; reused as S-LDS in pass 2
  __shared__ __align__(16) __bf16 KN[4096];    // Kn [64][64] swz
  __shared__ __align__(16) __bf16 VT[4096];    // V^T [feat][key] swz (pass 2 only)
  __shared__ uint16_t BITS[64 * 128];          // mask bits: [qrow][kword]  (16 KB)
  // total LDS = 40960 B -> 4 WG/CU

  const int tid = threadIdx.x;
  const int wid = tid >> 6;
  const int lane = tid & 63;
  const int c = lane & 15;   // MFMA col / A-row lane index
  const int g = lane >> 4;   // lane group 0..3

  // XCD-contiguous block swizzle (T1): batch's 32 WGs land on one XCD's L2.
  const int bid = blockIdx.x;
  const int flat = (bid & 7) * 128 + (bid >> 3);   // 1024 % 8 == 0 -> bijective
  const int b = flat >> 5;
  const int qt = flat & 31;

  const float* qb = q + ((size_t)b * Ln + (size_t)qt * 64) * Dn;
  const float* kb = kk + (size_t)b * Ln * Dn;
  const float* vb = v + (size_t)b * Ln * Dn;
  const int* mb = mask + (size_t)b * Ln * Ln + (size_t)qt * 64 * Ln;  // int32 mask
  float* attnb = attn + (size_t)b * Ln * Ln;

  // ---- Phase A: stage normalized Q (bf16, swizzled) ----
  stage_norm_tile(qb, QS, tid);

  // ---- Phase B: bit-pack int32 mask tile [64 x 2048] into LDS ----
  // Each thread packs one 16-element word per iter: 4x uint4 loads (64 B contiguous).
#pragma unroll 4
  for (int it = 0; it < 32; ++it) {
    const int wi = it * 256 + tid;                 // word index 0..8191 (= qrow*128 + kword)
    const uint4* p = (const uint4*)(mb + wi * 16); // 64B-aligned
    unsigned w = 0;
#pragma unroll
    for (int j = 0; j < 4; ++j) {
      uint4 x = p[j];
      w |= ((x.x & 1u) | ((x.y & 1u) << 1) | ((x.z & 1u) << 2) | ((x.w & 1u) << 3)) << (j * 4);
    }
    BITS[wi] = (uint16_t)w;
  }
  __syncthreads();

  // Q A-fragments: row = wid*16 + c, k(d-dim) = g*8..g*8+7 (+32 for half 1). Held in VGPRs.
  bf16x8_t a0 = *(const bf16x8_t*)&QS[swzi(wid * 16 + c, g * 8)];
  bf16x8_t a1 = *(const bf16x8_t*)&QS[swzi(wid * 16 + c, 32 + g * 8)];

  // ---- Pass 1: row sums of masked (cos+1) ----
  float rsum[4] = {0.f, 0.f, 0.f, 0.f};
  for (int kt = 0; kt < 32; ++kt) {
    __syncthreads();
    stage_norm_tile(kb + kt * 4096, KN, tid);
    __syncthreads();
#pragma unroll
    for (int ct = 0; ct < 4; ++ct) {
      bf16x8_t b0 = *(const bf16x8_t*)&KN[swzi(ct * 16 + c, g * 8)];
      bf16x8_t b1 = *(const bf16x8_t*)&KN[swzi(ct * 16 + c, 32 + g * 8)];
      f32x4_t acc = {0.f, 0.f, 0.f, 0.f};
      acc = __builtin_amdgcn_mfma_f32_16x16x32_bf16(a0, b0, acc, 0, 0, 0);
      acc = __builtin_amdgcn_mfma_f32_16x16x32_bf16(a1, b1, acc, 0, 0, 0);
#pragma unroll
      for (int r = 0; r < 4; ++r) {
        const int qrl = wid * 16 + g * 4 + r;
        const unsigned w = BITS[qrl * 128 + kt * 4 + ct];
        const float s = ((w >> c) & 1u) ? 0.f : (acc[r] + 1.f);
        rsum[r] += s;
      }
    }
  }
  float invr[4];
#pragma unroll
  for (int r = 0; r < 4; ++r) {
    float s = rsum[r];
    s += __shfl_xor(s, 1); s += __shfl_xor(s, 2);
    s += __shfl_xor(s, 4); s += __shfl_xor(s, 8);
    invr[r] = 1.0f / fmaxf(s, 1e-12f);
  }

  // ---- Pass 2: recompute scores, write normalized attn, MFMA PV ----
  f32x4_t oacc[4] = {{0.f,0.f,0.f,0.f},{0.f,0.f,0.f,0.f},{0.f,0.f,0.f,0.f},{0.f,0.f,0.f,0.f}};
  __bf16* SL = QS + wid * 1024;  // wave-private 16x64 S slice (Qn no longer needed)
  for (int kt = 0; kt < 32; ++kt) {
    __syncthreads();
    stage_norm_tile(kb + kt * 4096, KN, tid);
    stage_v_T(vb + kt * 4096, VT, tid);
    __syncthreads();
#pragma unroll
    for (int ct = 0; ct < 4; ++ct) {
      bf16x8_t b0 = *(const bf16x8_t*)&KN[swzi(ct * 16 + c, g * 8)];
      bf16x8_t b1 = *(const bf16x8_t*)&KN[swzi(ct * 16 + c, 32 + g * 8)];
      f32x4_t acc = {0.f, 0.f, 0.f, 0.f};
      acc = __builtin_amdgcn_mfma_f32_16x16x32_bf16(a0, b0, acc, 0, 0, 0);
      acc = __builtin_amdgcn_mfma_f32_16x16x32_bf16(a1, b1, acc, 0, 0, 0);
#pragma unroll
      for (int r = 0; r < 4; ++r) {
        const int qrl = wid * 16 + g * 4 + r;
        const unsigned w = BITS[qrl * 128 + kt * 4 + ct];
        const float s = ((w >> c) & 1u) ? 0.f : (acc[r] + 1.f);
        const float av = s * invr[r];
        attnb[(size_t)(qt * 64 + qrl) * Ln + kt * 64 + ct * 16 + c] = av;
        SL[swzi(g * 4 + r, ct * 16 + c)] = (__bf16)av;  // wave-private: no barrier needed
      }
    }
    // PV: A = S (16 q-rows x 64 keys), B = V^T tiles. Same-wave DS ordering via compiler waits.
    bf16x8_t sa0 = *(const bf16x8_t*)&SL[swzi(c, g * 8)];
    bf16x8_t sa1 = *(const bf16x8_t*)&SL[swzi(c, 32 + g * 8)];
#pragma unroll
    for (int nt = 0; nt < 4; ++nt) {
      bf16x8_t vb0 = *(const bf16x8_t*)&VT[swzi(nt * 16 + c, g * 8)];
      bf16x8_t vb1 = *(const bf16x8_t*)&VT[swzi(nt * 16 + c, 32 + g * 8)];
      oacc[nt] = __builtin_amdgcn_mfma_f32_16x16x32_bf16(sa0, vb0, oacc[nt], 0, 0, 0);
      oacc[nt] = __builtin_amdgcn_mfma_f32_16x16x32_bf16(sa1, vb1, oacc[nt], 0, 0, 0);
    }
  }

  // ---- Epilogue: write O ----
  float* ob = out + ((size_t)b * Ln + (size_t)qt * 64) * Dn;
#pragma unroll
  for (int nt = 0; nt < 4; ++nt)
#pragma unroll
    for (int r = 0; r < 4; ++r)
      ob[(wid * 16 + g * 4 + r) * 64 + nt * 16 + c] = oacc[nt][r];
}

extern "C" void kernel_launch(void* const* d_in, const int* in_sizes, int n_in,
                              void* d_out, int out_size, void* d_ws, size_t ws_size,
                              hipStream_t stream) {
  const float* q = (const float*)d_in[0];
  const float* k = (const float*)d_in[1];
  const float* v = (const float*)d_in[2];
  const int* mask = (const int*)d_in[3];     // harness maps integer/bool -> int32
  float* out = (float*)d_out;
  float* attn = out + (size_t)Bn * Ln * Dn;  // tuple: (output, attn) flat-concat
  dim3 grid(Bn * (Ln / 64));
  cosattn_kernel<<<grid, 256, 0, stream>>>(q, k, v, mask, out, attn);
}